// Round 1
// baseline (618.627 us; speedup 1.0000x reference)
//
#include <hip/hip_runtime.h>
#include <math.h>

typedef __bf16 bf16x8 __attribute__((ext_vector_type(8)));
typedef float f32x4 __attribute__((ext_vector_type(4)));

#define MFMA_BF16(a,b,c) __builtin_amdgcn_mfma_f32_16x16x32_bf16((a),(b),(c),0,0,0)

static constexpr int S_LEN = 2048;
static constexpr int DM    = 2048;   // model dim = H*Ld
static constexpr int NHEAD = 16;
static constexpr int LDH   = 128;    // head dim
static constexpr int BATCH = 2;

__device__ __forceinline__ unsigned short f2bf(float f) {
    unsigned u = __float_as_uint(f);
    u += 0x7fffu + ((u >> 16) & 1u);
    return (unsigned short)(u >> 16);
}
__device__ __forceinline__ float bf2f(unsigned short h) {
    return __uint_as_float(((unsigned)h) << 16);
}

// ---------------- fp32 -> bf16 elementwise (x) ----------------
__global__ void convert_f32_bf16(const float* __restrict__ in,
                                 unsigned short* __restrict__ out, int n4) {
    int idx = blockIdx.x * blockDim.x + threadIdx.x;
    if (idx >= n4) return;
    float4 v = reinterpret_cast<const float4*>(in)[idx];
    unsigned lo = (unsigned)f2bf(v.x) | ((unsigned)f2bf(v.y) << 16);
    unsigned hi = (unsigned)f2bf(v.z) | ((unsigned)f2bf(v.w) << 16);
    reinterpret_cast<uint2*>(out)[idx] = make_uint2(lo, hi);
}

// ---------------- fp32 (K x N) -> bf16 transposed (N x K) ----------------
__global__ void wconv_t(const float* __restrict__ W, unsigned short* __restrict__ Wt) {
    __shared__ unsigned short tile[32][33];
    int n0 = blockIdx.x * 32;       // col block in W (row block in Wt)
    int k0 = blockIdx.y * 32;       // row block in W
    int t = threadIdx.x;
    int ir = t >> 3, ic = (t & 7) * 4;
    float4 v = *reinterpret_cast<const float4*>(&W[(size_t)(k0 + ir) * DM + n0 + ic]);
    tile[ir][ic + 0] = f2bf(v.x);
    tile[ir][ic + 1] = f2bf(v.y);
    tile[ir][ic + 2] = f2bf(v.z);
    tile[ir][ic + 3] = f2bf(v.w);
    __syncthreads();
    unsigned short o0 = tile[ic + 0][ir];
    unsigned short o1 = tile[ic + 1][ir];
    unsigned short o2 = tile[ic + 2][ir];
    unsigned short o3 = tile[ic + 3][ir];
    unsigned lo = (unsigned)o0 | ((unsigned)o1 << 16);
    unsigned hi = (unsigned)o2 | ((unsigned)o3 << 16);
    *reinterpret_cast<uint2*>(&Wt[(size_t)(n0 + ir) * DM + k0 + ic]) = make_uint2(lo, hi);
}

// ---------------- bf16 GEMM: C = A(MxK) * Bt(NxK)^T + bias ----------------
// MODE 0: store bf16 into (B, H, S, Ld) permuted layout (QKV)
// MODE 1: store fp32 row-major (final output)
template<int MODE>
__global__ __launch_bounds__(256, 2) void gemm_bf16(
    const unsigned short* __restrict__ A,
    const unsigned short* __restrict__ Bt,
    const float* __restrict__ bias,
    void* __restrict__ outp)
{
    const int K = DM;  // 2048
    __shared__ unsigned short As[128][40];  // pad to 40 (80B rows, 16B-aligned, 2-way banks)
    __shared__ unsigned short Bs[128][40];
    int t = threadIdx.x;
    int m0 = blockIdx.y * 128, n0 = blockIdx.x * 128;
    int lane = t & 63, i16 = lane & 15, quad = lane >> 4;
    int w = t >> 6;
    int wm = (w >> 1) * 64, wn = (w & 1) * 64;

    f32x4 acc[4][4];
    const f32x4 z4 = {0.f, 0.f, 0.f, 0.f};
    for (int mi = 0; mi < 4; ++mi)
        for (int ni = 0; ni < 4; ++ni) acc[mi][ni] = z4;

    int rowA = t >> 2;            // 0..63
    int segA = (t & 3) * 8;       // element offset 0/8/16/24

    for (int kk = 0; kk < K; kk += 32) {
        __syncthreads();
        uint4 a0 = *reinterpret_cast<const uint4*>(&A [(size_t)(m0 + rowA)      * K + kk + segA]);
        uint4 a1 = *reinterpret_cast<const uint4*>(&A [(size_t)(m0 + rowA + 64) * K + kk + segA]);
        uint4 b0 = *reinterpret_cast<const uint4*>(&Bt[(size_t)(n0 + rowA)      * K + kk + segA]);
        uint4 b1 = *reinterpret_cast<const uint4*>(&Bt[(size_t)(n0 + rowA + 64) * K + kk + segA]);
        *reinterpret_cast<uint4*>(&As[rowA][segA])      = a0;
        *reinterpret_cast<uint4*>(&As[rowA + 64][segA]) = a1;
        *reinterpret_cast<uint4*>(&Bs[rowA][segA])      = b0;
        *reinterpret_cast<uint4*>(&Bs[rowA + 64][segA]) = b1;
        __syncthreads();

        bf16x8 aF[4], bF[4];
        for (int mi = 0; mi < 4; ++mi)
            aF[mi] = *reinterpret_cast<const bf16x8*>(&As[wm + mi * 16 + i16][quad * 8]);
        for (int ni = 0; ni < 4; ++ni)
            bF[ni] = *reinterpret_cast<const bf16x8*>(&Bs[wn + ni * 16 + i16][quad * 8]);
        for (int mi = 0; mi < 4; ++mi)
            for (int ni = 0; ni < 4; ++ni)
                acc[mi][ni] = MFMA_BF16(aF[mi], bF[ni], acc[mi][ni]);
    }

    for (int mi = 0; mi < 4; ++mi) {
        for (int ni = 0; ni < 4; ++ni) {
            int nn = n0 + wn + ni * 16 + i16;
            float bv = bias[nn];
            for (int r = 0; r < 4; ++r) {
                int mm = m0 + wm + mi * 16 + quad * 4 + r;
                float v = acc[mi][ni][r] + bv;
                if (MODE == 0) {
                    int b = mm >> 11, s = mm & (S_LEN - 1);
                    int h = nn >> 7,  d = nn & (LDH - 1);
                    ((unsigned short*)outp)[(((size_t)(b * NHEAD + h)) * S_LEN + s) * LDH + d] = f2bf(v);
                } else {
                    ((float*)outp)[(size_t)mm * DM + nn] = v;
                }
            }
        }
    }
}

// ---------------- RoPE in place on q and k, (B,H,S,Ld) bf16 ----------------
// lane i handles pair (2i, 2i+1) -> outputs at i and 64+i
__global__ void rope_kernel(unsigned short* __restrict__ q, unsigned short* __restrict__ k) {
    int w = threadIdx.x >> 6, lane = threadIdx.x & 63;
    int rowid = blockIdx.x * 4 + w;              // 0 .. 131071
    unsigned short* base = (rowid < BATCH * NHEAD * S_LEN) ? q : k;
    int idx = rowid & (BATCH * NHEAD * S_LEN - 1);
    int s = idx & (S_LEN - 1);
    unsigned short* row = base + (size_t)idx * LDH;
    unsigned pair = reinterpret_cast<unsigned*>(row)[lane];
    float x1 = bf2f((unsigned short)(pair & 0xffff));
    float x2 = bf2f((unsigned short)(pair >> 16));
    // inv_freq = 10000^(-2*lane/128), computed in double then rounded
    float freq = (float)exp(-(double)(2 * lane) / 128.0 * 9.210340371976184);
    float angle = (float)s * freq;
    float c = cosf(angle), sn = sinf(angle);
    float o1 = x1 * c - x2 * sn;
    float o2 = x1 * sn + x2 * c;
    row[lane]      = f2bf(o1);
    row[64 + lane] = f2bf(o2);
}

// ---------------- V (B,H,S,Ld) -> Vt (B,H,Ld,S) ----------------
__global__ void vtrans(const unsigned short* __restrict__ v, unsigned short* __restrict__ vt) {
    __shared__ unsigned short tile[32][33];
    int bh = blockIdx.z;
    int s0 = blockIdx.x * 32, d0 = blockIdx.y * 32;
    const unsigned short* vin = v + (size_t)bh * S_LEN * LDH;
    unsigned short* vout = vt + (size_t)bh * S_LEN * LDH;
    int t = threadIdx.x;
    int ir = t >> 3, ic = (t & 7) * 4;
    uint2 rv = *reinterpret_cast<const uint2*>(&vin[(size_t)(s0 + ir) * LDH + d0 + ic]);
    tile[ir][ic + 0] = (unsigned short)(rv.x & 0xffff);
    tile[ir][ic + 1] = (unsigned short)(rv.x >> 16);
    tile[ir][ic + 2] = (unsigned short)(rv.y & 0xffff);
    tile[ir][ic + 3] = (unsigned short)(rv.y >> 16);
    __syncthreads();
    unsigned lo = (unsigned)tile[ic + 0][ir] | ((unsigned)tile[ic + 1][ir] << 16);
    unsigned hi = (unsigned)tile[ic + 2][ir] | ((unsigned)tile[ic + 3][ir] << 16);
    *reinterpret_cast<uint2*>(&vout[(size_t)(d0 + ir) * S_LEN + s0 + ic]) = make_uint2(lo, hi);
}

// ---------------- flash attention (anti-causal mask: keep k >= q) ----------------
// grid (S/64, B*H); block 256 = 4 waves, wave w owns q rows [q0+16w, q0+16w+16)
__global__ __launch_bounds__(256, 2) void attn_kernel(
    const unsigned short* __restrict__ q,
    const unsigned short* __restrict__ k,
    const unsigned short* __restrict__ vt,
    unsigned short* __restrict__ att)
{
    __shared__ unsigned short Ks[32][136];   // 32 keys x 128 d  (pad 136)
    __shared__ unsigned short Vs[128][40];   // 128 d x 32 keys  (pad 40)
    __shared__ unsigned short Ps[4][16][40]; // per-wave P tile 16x32 (pad 40)

    int bh = blockIdx.y;
    int b = bh >> 4, h = bh & (NHEAD - 1);
    int q0 = blockIdx.x * 64;
    int t = threadIdx.x, w = t >> 6, lane = t & 63;
    int i16 = lane & 15, quad = lane >> 4;
    int qbase = q0 + w * 16;

    const unsigned short* qrow = q + ((size_t)bh * S_LEN + qbase + i16) * LDH;
    bf16x8 qf[4];
    for (int c = 0; c < 4; ++c)
        qf[c] = *reinterpret_cast<const bf16x8*>(qrow + c * 32 + quad * 8);

    const f32x4 z4 = {0.f, 0.f, 0.f, 0.f};
    f32x4 o[8];
    for (int dt = 0; dt < 8; ++dt) o[dt] = z4;
    float m_i[4], l_i[4];
    for (int r = 0; r < 4; ++r) { m_i[r] = -INFINITY; l_i[r] = 0.f; }

    const float scale = 0.08838834764831845f;  // 1/sqrt(128)
    const unsigned short* kbh  = k  + (size_t)bh * S_LEN * LDH;
    const unsigned short* vtbh = vt + (size_t)bh * LDH * S_LEN;

    // anti-causal: row q attends keys [q, S). Block min q = q0.
    for (int kk0 = q0; kk0 < S_LEN; kk0 += 32) {
        __syncthreads();
        {   // stage K tile: 32 rows x 128 d = 512 x 16B segs
            int sg = t;
            int kr = sg >> 4, ksc = (sg & 15) * 8;
            *reinterpret_cast<uint4*>(&Ks[kr][ksc]) =
                *reinterpret_cast<const uint4*>(&kbh[(size_t)(kk0 + kr) * LDH + ksc]);
            sg = t + 256; kr = sg >> 4; ksc = (sg & 15) * 8;
            *reinterpret_cast<uint4*>(&Ks[kr][ksc]) =
                *reinterpret_cast<const uint4*>(&kbh[(size_t)(kk0 + kr) * LDH + ksc]);
            // stage Vt tile: 128 d x 32 keys = 512 x 16B segs
            int d = t >> 2, vs = (t & 3) * 8;
            *reinterpret_cast<uint4*>(&Vs[d][vs]) =
                *reinterpret_cast<const uint4*>(&vtbh[(size_t)d * S_LEN + kk0 + vs]);
            d += 64;
            *reinterpret_cast<uint4*>(&Vs[d][vs]) =
                *reinterpret_cast<const uint4*>(&vtbh[(size_t)d * S_LEN + kk0 + vs]);
        }
        __syncthreads();

        // QK^T: two 16x16 score subtiles over 32 keys
        f32x4 s0 = z4, s1 = z4;
        for (int c = 0; c < 4; ++c) {
            bf16x8 k0f = *reinterpret_cast<const bf16x8*>(&Ks[i16     ][c * 32 + quad * 8]);
            bf16x8 k1f = *reinterpret_cast<const bf16x8*>(&Ks[16 + i16][c * 32 + quad * 8]);
            s0 = MFMA_BF16(qf[c], k0f, s0);
            s1 = MFMA_BF16(qf[c], k1f, s1);
        }

        for (int r = 0; r < 4; ++r) {
            int qg = qbase + quad * 4 + r;
            float a0 = s0[r] * scale;
            float a1 = s1[r] * scale;
            if (kk0 + i16      < qg) a0 = -INFINITY;   // keep k >= q
            if (kk0 + 16 + i16 < qg) a1 = -INFINITY;
            float rm = fmaxf(a0, a1);
            rm = fmaxf(rm, __shfl_xor(rm, 1));
            rm = fmaxf(rm, __shfl_xor(rm, 2));
            rm = fmaxf(rm, __shfl_xor(rm, 4));
            rm = fmaxf(rm, __shfl_xor(rm, 8));
            float mnew  = fmaxf(m_i[r], rm);
            float msafe = fmaxf(mnew, -1e37f);         // NaN guard for fully-masked chunks
            float alpha = __expf(m_i[r] - msafe);
            float p0 = __expf(a0 - msafe);
            float p1 = __expf(a1 - msafe);
            float rs = p0 + p1;
            rs += __shfl_xor(rs, 1);
            rs += __shfl_xor(rs, 2);
            rs += __shfl_xor(rs, 4);
            rs += __shfl_xor(rs, 8);
            l_i[r] = l_i[r] * alpha + rs;
            m_i[r] = mnew;
            for (int dt = 0; dt < 8; ++dt) o[dt][r] *= alpha;
            Ps[w][quad * 4 + r][i16]      = f2bf(p0);
            Ps[w][quad * 4 + r][16 + i16] = f2bf(p1);
        }
        __syncthreads();

        // PV: P(16x32) in A-layout from LDS, Vt fragments contiguous
        bf16x8 pf = *reinterpret_cast<const bf16x8*>(&Ps[w][i16][quad * 8]);
        for (int dt = 0; dt < 8; ++dt) {
            bf16x8 vf = *reinterpret_cast<const bf16x8*>(&Vs[dt * 16 + i16][quad * 8]);
            o[dt] = MFMA_BF16(pf, vf, o[dt]);
        }
    }

    // epilogue: normalize, store to (B, S, H*Ld) bf16
    for (int r = 0; r < 4; ++r) {
        int qg = qbase + quad * 4 + r;
        float inv = 1.0f / l_i[r];
        unsigned short* orow = att + ((size_t)b * S_LEN + qg) * DM + h * LDH;
        for (int dt = 0; dt < 8; ++dt)
            orow[dt * 16 + i16] = f2bf(o[dt][r] * inv);
    }
}

// ---------------- launcher ----------------
extern "C" void kernel_launch(void* const* d_in, const int* in_sizes, int n_in,
                              void* d_out, int out_size, void* d_ws, size_t ws_size,
                              hipStream_t stream) {
    const float* x  = (const float*)d_in[0];
    const float* Wq = (const float*)d_in[2];
    const float* bq = (const float*)d_in[3];
    const float* Wk = (const float*)d_in[4];
    const float* bk = (const float*)d_in[5];
    const float* Wv = (const float*)d_in[6];
    const float* bv = (const float*)d_in[7];
    const float* Wo = (const float*)d_in[8];
    const float* bo = (const float*)d_in[9];

    char* ws = (char*)d_ws;
    unsigned short* xb  = (unsigned short*)(ws);                  // 16 MB  (4096x2048 bf16)
    unsigned short* Wqt = (unsigned short*)(ws + 16777216);       // 8 MB each (2048x2048 bf16, NxK)
    unsigned short* Wkt = (unsigned short*)(ws + 25165824);
    unsigned short* Wvt = (unsigned short*)(ws + 33554432);
    unsigned short* Wot = (unsigned short*)(ws + 41943040);
    unsigned short* qb  = (unsigned short*)(ws + 50331648);       // 16 MB (B,H,S,Ld)
    unsigned short* kb  = (unsigned short*)(ws + 67108864);
    unsigned short* vb  = (unsigned short*)(ws + 83886080);
    unsigned short* vtb = (unsigned short*)(ws + 100663296);      // (B,H,Ld,S)
    unsigned short* att = (unsigned short*)(ws + 117440512);      // (B,S,H*Ld)

    // 1) conversions
    convert_f32_bf16<<<8192, 256, 0, stream>>>(x, xb, (BATCH * S_LEN * DM) / 4);
    wconv_t<<<dim3(64, 64), 256, 0, stream>>>(Wq, Wqt);
    wconv_t<<<dim3(64, 64), 256, 0, stream>>>(Wk, Wkt);
    wconv_t<<<dim3(64, 64), 256, 0, stream>>>(Wv, Wvt);
    wconv_t<<<dim3(64, 64), 256, 0, stream>>>(Wo, Wot);

    // 2) QKV projections (M=4096, N=2048, K=2048)
    dim3 ggrid(DM / 128, (BATCH * S_LEN) / 128);
    gemm_bf16<0><<<ggrid, 256, 0, stream>>>(xb, Wqt, bq, qb);
    gemm_bf16<0><<<ggrid, 256, 0, stream>>>(xb, Wkt, bk, kb);
    gemm_bf16<0><<<ggrid, 256, 0, stream>>>(xb, Wvt, bv, vb);

    // 3) RoPE on q,k (in place); transpose v
    rope_kernel<<<(2 * BATCH * NHEAD * S_LEN) / 4, 256, 0, stream>>>(qb, kb);
    vtrans<<<dim3(S_LEN / 32, LDH / 32, BATCH * NHEAD), 256, 0, stream>>>(vb, vtb);

    // 4) attention
    attn_kernel<<<dim3(S_LEN / 64, BATCH * NHEAD), 256, 0, stream>>>(qb, kb, vtb, att);

    // 5) output projection, fp32 out
    gemm_bf16<1><<<ggrid, 256, 0, stream>>>(att, Wot, bo, (float*)d_out);
}

// Round 2
// 483.762 us; speedup vs baseline: 1.2788x; 1.2788x over previous
//
#include <hip/hip_runtime.h>
#include <math.h>

typedef __bf16 bf16x8 __attribute__((ext_vector_type(8)));
typedef float f32x4 __attribute__((ext_vector_type(4)));

#define MFMA_BF16(a,b,c) __builtin_amdgcn_mfma_f32_16x16x32_bf16((a),(b),(c),0,0,0)

static constexpr int S_LEN = 2048;
static constexpr int DM    = 2048;   // model dim = H*Ld
static constexpr int NHEAD = 16;
static constexpr int LDH   = 128;    // head dim
static constexpr int BATCH = 2;

__device__ __forceinline__ unsigned short f2bf(float f) {
    unsigned u = __float_as_uint(f);
    u += 0x7fffu + ((u >> 16) & 1u);
    return (unsigned short)(u >> 16);
}
__device__ __forceinline__ float bf2f(unsigned short h) {
    return __uint_as_float(((unsigned)h) << 16);
}

// async global->LDS, 16B per lane. LDS dest must be wave-uniform base + lane*16.
__device__ __forceinline__ void ld_lds16(const void* g, void* l) {
    __builtin_amdgcn_global_load_lds(
        (const __attribute__((address_space(1))) unsigned int*)g,
        (__attribute__((address_space(3))) unsigned int*)l, 16, 0, 0);
}

// ---------------- fp32 -> bf16 elementwise (x) ----------------
__global__ void convert_f32_bf16(const float* __restrict__ in,
                                 unsigned short* __restrict__ out, int n4) {
    int idx = blockIdx.x * blockDim.x + threadIdx.x;
    if (idx >= n4) return;
    float4 v = reinterpret_cast<const float4*>(in)[idx];
    unsigned lo = (unsigned)f2bf(v.x) | ((unsigned)f2bf(v.y) << 16);
    unsigned hi = (unsigned)f2bf(v.z) | ((unsigned)f2bf(v.w) << 16);
    reinterpret_cast<uint2*>(out)[idx] = make_uint2(lo, hi);
}

// ---------------- fp32 (K x N) -> bf16 transposed (N x K) ----------------
__global__ void wconv_t(const float* __restrict__ W, unsigned short* __restrict__ Wt) {
    __shared__ unsigned short tile[32][33];
    int n0 = blockIdx.x * 32;
    int k0 = blockIdx.y * 32;
    int t = threadIdx.x;
    int ir = t >> 3, ic = (t & 7) * 4;
    float4 v = *reinterpret_cast<const float4*>(&W[(size_t)(k0 + ir) * DM + n0 + ic]);
    tile[ir][ic + 0] = f2bf(v.x);
    tile[ir][ic + 1] = f2bf(v.y);
    tile[ir][ic + 2] = f2bf(v.z);
    tile[ir][ic + 3] = f2bf(v.w);
    __syncthreads();
    unsigned lo = (unsigned)tile[ic + 0][ir] | ((unsigned)tile[ic + 1][ir] << 16);
    unsigned hi = (unsigned)tile[ic + 2][ir] | ((unsigned)tile[ic + 3][ir] << 16);
    *reinterpret_cast<uint2*>(&Wt[(size_t)(n0 + ir) * DM + k0 + ic]) = make_uint2(lo, hi);
}

// ---------------- bf16 GEMM, m97-style async staging + XOR swizzle ----------------
// MODE 0: fused QKV, Bt has N=6144 rows; store bf16 to (which,B,H,S,Ld)
// MODE 1: store fp32 row-major M x 2048 (final output)
template<int MODE>
__global__ __launch_bounds__(256, 2) void gemm_bf16(
    const unsigned short* __restrict__ A,
    const unsigned short* __restrict__ Bt,
    const float* __restrict__ b0, const float* __restrict__ b1,
    const float* __restrict__ b2,
    void* __restrict__ outp)
{
    const int K = DM;
    __shared__ unsigned short As[128 * 32];  // unpadded: global_load_lds needs lane-contiguous
    __shared__ unsigned short Bs[128 * 32];
    int t = threadIdx.x;
    int m0 = blockIdx.y * 128, n0 = blockIdx.x * 128;
    int lane = t & 63, i16 = lane & 15, quad = lane >> 4;
    int w = t >> 6;
    int wm = (w >> 1) * 64, wn = (w & 1) * 64;

    f32x4 acc[4][4];
    const f32x4 z4 = {0.f, 0.f, 0.f, 0.f};
    for (int mi = 0; mi < 4; ++mi)
        for (int ni = 0; ni < 4; ++ni) acc[mi][ni] = z4;

    for (int kk = 0; kk < K; kk += 32) {
        __syncthreads();
#pragma unroll
        for (int j = 0; j < 2; ++j) {
            int off = j * 4096 + w * 1024 + lane * 16;   // byte offset in As/Bs
            int row = off >> 6;                          // 64B per row (32 bf16)
            int g = ((off >> 4) & 3) ^ ((row >> 1) & 3); // XOR swizzle absorbed in src addr
            ld_lds16(&A [(size_t)(m0 + row) * K + kk + g * 8], (char*)As + off);
            ld_lds16(&Bt[(size_t)(n0 + row) * K + kk + g * 8], (char*)Bs + off);
        }
        __syncthreads();

        bf16x8 aF[4], bF[4];
#pragma unroll
        for (int mi = 0; mi < 4; ++mi) {
            int rA = wm + mi * 16 + i16;
            aF[mi] = *reinterpret_cast<const bf16x8*>(
                (const char*)As + rA * 64 + ((quad ^ ((rA >> 1) & 3)) * 16));
        }
#pragma unroll
        for (int ni = 0; ni < 4; ++ni) {
            int rB = wn + ni * 16 + i16;
            bF[ni] = *reinterpret_cast<const bf16x8*>(
                (const char*)Bs + rB * 64 + ((quad ^ ((rB >> 1) & 3)) * 16));
        }
#pragma unroll
        for (int mi = 0; mi < 4; ++mi)
#pragma unroll
            for (int ni = 0; ni < 4; ++ni)
                acc[mi][ni] = MFMA_BF16(aF[mi], bF[ni], acc[mi][ni]);
    }

    for (int mi = 0; mi < 4; ++mi) {
        for (int ni = 0; ni < 4; ++ni) {
            int nn = n0 + wn + ni * 16 + i16;
            float bv;
            if (MODE == 0) {
                int which = nn >> 11;  // uniform per block (n0 multiple of 128)
                const float* bp = (which == 0) ? b0 : ((which == 1) ? b1 : b2);
                bv = bp[nn & (DM - 1)];
            } else {
                bv = b0[nn];
            }
            for (int r = 0; r < 4; ++r) {
                int mm = m0 + wm + mi * 16 + quad * 4 + r;
                float v = acc[mi][ni][r] + bv;
                if (MODE == 0) {
                    int which = nn >> 11;
                    int within = nn & (DM - 1);
                    int b = mm >> 11, s = mm & (S_LEN - 1);
                    int h = within >> 7, d = within & (LDH - 1);
                    size_t oidx = (((size_t)which * BATCH * NHEAD + b * NHEAD + h) * S_LEN + s) * LDH + d;
                    ((unsigned short*)outp)[oidx] = f2bf(v);
                } else {
                    ((float*)outp)[(size_t)mm * DM + nn] = v;
                }
            }
        }
    }
}

// ---------------- RoPE in place; q additionally pre-scaled by 1/sqrt(Ld) ----------------
__global__ void rope_kernel(unsigned short* __restrict__ q, unsigned short* __restrict__ k) {
    int w = threadIdx.x >> 6, lane = threadIdx.x & 63;
    int rowid = blockIdx.x * 4 + w;
    bool isq = (rowid < BATCH * NHEAD * S_LEN);
    unsigned short* base = isq ? q : k;
    int idx = rowid & (BATCH * NHEAD * S_LEN - 1);
    int s = idx & (S_LEN - 1);
    unsigned short* row = base + (size_t)idx * LDH;
    unsigned pair = reinterpret_cast<unsigned*>(row)[lane];
    float x1 = bf2f((unsigned short)(pair & 0xffff));
    float x2 = bf2f((unsigned short)(pair >> 16));
    float freq = (float)exp(-(double)(2 * lane) / 128.0 * 9.210340371976184);
    float angle = (float)s * freq;
    float c = cosf(angle), sn = sinf(angle);
    float sc = isq ? 0.08838834764831845f : 1.0f;  // fold 1/sqrt(128) into q
    row[lane]      = f2bf((x1 * c - x2 * sn) * sc);
    row[64 + lane] = f2bf((x1 * sn + x2 * c) * sc);
}

// ---------------- V (B,H,S,Ld) -> Vt (B,H,Ld,S) ----------------
__global__ void vtrans(const unsigned short* __restrict__ v, unsigned short* __restrict__ vt) {
    __shared__ unsigned short tile[32][33];
    int bh = blockIdx.z;
    int s0 = blockIdx.x * 32, d0 = blockIdx.y * 32;
    const unsigned short* vin = v + (size_t)bh * S_LEN * LDH;
    unsigned short* vout = vt + (size_t)bh * S_LEN * LDH;
    int t = threadIdx.x;
    int ir = t >> 3, ic = (t & 7) * 4;
    uint2 rv = *reinterpret_cast<const uint2*>(&vin[(size_t)(s0 + ir) * LDH + d0 + ic]);
    tile[ir][ic + 0] = (unsigned short)(rv.x & 0xffff);
    tile[ir][ic + 1] = (unsigned short)(rv.x >> 16);
    tile[ir][ic + 2] = (unsigned short)(rv.y & 0xffff);
    tile[ir][ic + 3] = (unsigned short)(rv.y >> 16);
    __syncthreads();
    unsigned lo = (unsigned)tile[ic + 0][ir] | ((unsigned)tile[ic + 1][ir] << 16);
    unsigned hi = (unsigned)tile[ic + 2][ir] | ((unsigned)tile[ic + 3][ir] << 16);
    *reinterpret_cast<uint2*>(&vout[(size_t)(d0 + ir) * S_LEN + s0 + ic]) = make_uint2(lo, hi);
}

// ---------------- flash attention v2 (anti-causal: keep k >= q) ----------------
// No-max online softmax: o += exp(s)*v, l += exp(s); reduce l once at the end.
// 64-key chunks, async-staged swizzled LDS, wave-uniform mask branch.
__global__ __launch_bounds__(256, 2) void attn_kernel(
    const unsigned short* __restrict__ q,
    const unsigned short* __restrict__ k,
    const unsigned short* __restrict__ vt,
    unsigned short* __restrict__ att)
{
    __shared__ unsigned short Ks[64 * 128];   // key-major, 256B rows, group-swizzled
    __shared__ unsigned short Vs[128 * 64];   // d-major, 128B rows, group-swizzled
    __shared__ unsigned short Ps[4][16][72];  // per-wave P tile (pad 72: conflict-free)

    int bh = blockIdx.y;
    int b = bh >> 4, h = bh & (NHEAD - 1);
    int q0 = blockIdx.x * 64;
    int t = threadIdx.x, w = t >> 6, lane = t & 63;
    int i16 = lane & 15, quad = lane >> 4;
    int qbase = q0 + w * 16;

    const unsigned short* qrow = q + ((size_t)bh * S_LEN + qbase + i16) * LDH;
    bf16x8 qf[4];
#pragma unroll
    for (int c = 0; c < 4; ++c)
        qf[c] = *reinterpret_cast<const bf16x8*>(qrow + c * 32 + quad * 8);

    const f32x4 z4 = {0.f, 0.f, 0.f, 0.f};
    f32x4 o[8];
#pragma unroll
    for (int dt = 0; dt < 8; ++dt) o[dt] = z4;
    float l_i[4] = {0.f, 0.f, 0.f, 0.f};

    const unsigned short* kbh  = k  + (size_t)bh * S_LEN * LDH;
    const unsigned short* vtbh = vt + (size_t)bh * LDH * S_LEN;

    for (int kk0 = q0; kk0 < S_LEN; kk0 += 64) {
        __syncthreads();
#pragma unroll
        for (int j = 0; j < 4; ++j) {
            int off = j * 4096 + w * 1024 + lane * 16;
            // K tile: row=key (256B, 16 groups), swizzle g ^= key&15
            int key = off >> 8;
            int gk = ((off >> 4) & 15) ^ (key & 15);
            ld_lds16(&kbh[(size_t)(kk0 + key) * LDH + gk * 8], (char*)Ks + off);
            // V tile: row=d (128B, 8 groups), swizzle g ^= d&7
            int d = off >> 7;
            int gv = ((off >> 4) & 7) ^ (d & 7);
            ld_lds16(&vtbh[(size_t)d * S_LEN + kk0 + gv * 8], (char*)Vs + off);
        }
        __syncthreads();

        // QK^T: 4 key-subtiles of 16
        f32x4 s[4] = {z4, z4, z4, z4};
#pragma unroll
        for (int c = 0; c < 4; ++c) {
#pragma unroll
            for (int kn = 0; kn < 4; ++kn) {
                int key = kn * 16 + i16;
                int g = (c * 4 + quad) ^ i16;   // key&15 == i16
                bf16x8 kf = *reinterpret_cast<const bf16x8*>(
                    (const char*)Ks + key * 256 + g * 16);
                s[kn] = MFMA_BF16(qf[c], kf, s[kn]);
            }
        }

        // softmax (no running max; scale pre-folded into q)
        bool need_mask = (kk0 < qbase + 16);  // wave-uniform: only first chunk
        if (need_mask) {
#pragma unroll
            for (int kn = 0; kn < 4; ++kn)
#pragma unroll
                for (int r = 0; r < 4; ++r) {
                    int key = kk0 + kn * 16 + i16;
                    int qg = qbase + quad * 4 + r;
                    float p = (key >= qg) ? __expf(s[kn][r]) : 0.f;
                    l_i[r] += p;
                    Ps[w][quad * 4 + r][kn * 16 + i16] = f2bf(p);
                }
        } else {
#pragma unroll
            for (int kn = 0; kn < 4; ++kn)
#pragma unroll
                for (int r = 0; r < 4; ++r) {
                    float p = __expf(s[kn][r]);
                    l_i[r] += p;
                    Ps[w][quad * 4 + r][kn * 16 + i16] = f2bf(p);
                }
        }
        // Ps is per-wave: no barrier needed (within-wave lgkmcnt ordering)

        // PV: two 32-key halves
#pragma unroll
        for (int hh = 0; hh < 2; ++hh) {
            bf16x8 pf = *reinterpret_cast<const bf16x8*>(&Ps[w][i16][hh * 32 + quad * 8]);
#pragma unroll
            for (int dt = 0; dt < 8; ++dt) {
                int d = dt * 16 + i16;
                int g = (hh * 4 + quad) ^ (i16 & 7);
                bf16x8 vf = *reinterpret_cast<const bf16x8*>(
                    (const char*)Vs + d * 128 + g * 16);
                o[dt] = MFMA_BF16(pf, vf, o[dt]);
            }
        }
    }

    // epilogue: reduce l across the 16 key-lanes once, normalize, store
#pragma unroll
    for (int r = 0; r < 4; ++r) {
        float rs = l_i[r];
        rs += __shfl_xor(rs, 1);
        rs += __shfl_xor(rs, 2);
        rs += __shfl_xor(rs, 4);
        rs += __shfl_xor(rs, 8);
        float inv = 1.0f / rs;
        int qg = qbase + quad * 4 + r;
        unsigned short* orow = att + ((size_t)b * S_LEN + qg) * DM + h * LDH;
#pragma unroll
        for (int dt = 0; dt < 8; ++dt)
            orow[dt * 16 + i16] = f2bf(o[dt][r] * inv);
    }
}

// ---------------- launcher ----------------
extern "C" void kernel_launch(void* const* d_in, const int* in_sizes, int n_in,
                              void* d_out, int out_size, void* d_ws, size_t ws_size,
                              hipStream_t stream) {
    const float* x  = (const float*)d_in[0];
    const float* Wq = (const float*)d_in[2];
    const float* bq = (const float*)d_in[3];
    const float* Wk = (const float*)d_in[4];
    const float* bk = (const float*)d_in[5];
    const float* Wv = (const float*)d_in[6];
    const float* bv = (const float*)d_in[7];
    const float* Wo = (const float*)d_in[8];
    const float* bo = (const float*)d_in[9];

    char* ws = (char*)d_ws;
    unsigned short* xb  = (unsigned short*)(ws);                  // 16 MB
    unsigned short* Wqt = (unsigned short*)(ws + 16777216);       // 8 MB each, contiguous (QKV concat)
    unsigned short* Wkt = (unsigned short*)(ws + 25165824);
    unsigned short* Wvt = (unsigned short*)(ws + 33554432);
    unsigned short* Wot = (unsigned short*)(ws + 41943040);
    unsigned short* qb  = (unsigned short*)(ws + 50331648);       // 16 MB each, contiguous (q,k,v)
    unsigned short* kb  = (unsigned short*)(ws + 67108864);
    unsigned short* vb  = (unsigned short*)(ws + 83886080);
    unsigned short* vtb = (unsigned short*)(ws + 100663296);
    unsigned short* att = (unsigned short*)(ws + 117440512);

    convert_f32_bf16<<<8192, 256, 0, stream>>>(x, xb, (BATCH * S_LEN * DM) / 4);
    wconv_t<<<dim3(64, 64), 256, 0, stream>>>(Wq, Wqt);
    wconv_t<<<dim3(64, 64), 256, 0, stream>>>(Wk, Wkt);
    wconv_t<<<dim3(64, 64), 256, 0, stream>>>(Wv, Wvt);
    wconv_t<<<dim3(64, 64), 256, 0, stream>>>(Wo, Wot);

    // fused QKV projection: M=4096, N=6144, K=2048
    gemm_bf16<0><<<dim3(3 * DM / 128, (BATCH * S_LEN) / 128), 256, 0, stream>>>(
        xb, Wqt, bq, bk, bv, qb);

    rope_kernel<<<(2 * BATCH * NHEAD * S_LEN) / 4, 256, 0, stream>>>(qb, kb);
    vtrans<<<dim3(S_LEN / 32, LDH / 32, BATCH * NHEAD), 256, 0, stream>>>(vb, vtb);

    attn_kernel<<<dim3(S_LEN / 64, BATCH * NHEAD), 256, 0, stream>>>(qb, kb, vtb, att);

    // output projection: M=4096, N=2048, K=2048, fp32 out
    gemm_bf16<1><<<dim3(DM / 128, (BATCH * S_LEN) / 128), 256, 0, stream>>>(
        att, Wot, bo, bo, bo, (float*)d_out);
}

// Round 3
// 412.302 us; speedup vs baseline: 1.5004x; 1.1733x over previous
//
#include <hip/hip_runtime.h>
#include <math.h>

typedef __bf16 bf16x8 __attribute__((ext_vector_type(8)));
typedef float f32x4 __attribute__((ext_vector_type(4)));

#define MFMA_BF16(a,b,c) __builtin_amdgcn_mfma_f32_16x16x32_bf16((a),(b),(c),0,0,0)

static constexpr int S_LEN = 2048;
static constexpr int DM    = 2048;
static constexpr int NHEAD = 16;
static constexpr int LDH   = 128;
static constexpr int BATCH = 2;

__device__ __forceinline__ unsigned short f2bf(float f) {
    unsigned u = __float_as_uint(f);
    u += 0x7fffu + ((u >> 16) & 1u);
    return (unsigned short)(u >> 16);
}
__device__ __forceinline__ float bf2f(unsigned short h) {
    return __uint_as_float(((unsigned)h) << 16);
}
__device__ __forceinline__ float fexp2(float x) {
#if __has_builtin(__builtin_amdgcn_exp2f)
    return __builtin_amdgcn_exp2f(x);
#else
    return exp2f(x);
#endif
}

// async global->LDS, 16B per lane. LDS dest must be wave-uniform base + lane*16.
__device__ __forceinline__ void ld_lds16(const void* g, void* l) {
    __builtin_amdgcn_global_load_lds(
        (const __attribute__((address_space(1))) unsigned int*)g,
        (__attribute__((address_space(3))) unsigned int*)l, 16, 0, 0);
}

// ---------------- fp32 -> bf16 elementwise (x) ----------------
__global__ void convert_f32_bf16(const float* __restrict__ in,
                                 unsigned short* __restrict__ out, int n4) {
    int idx = blockIdx.x * blockDim.x + threadIdx.x;
    if (idx >= n4) return;
    float4 v = reinterpret_cast<const float4*>(in)[idx];
    unsigned lo = (unsigned)f2bf(v.x) | ((unsigned)f2bf(v.y) << 16);
    unsigned hi = (unsigned)f2bf(v.z) | ((unsigned)f2bf(v.w) << 16);
    reinterpret_cast<uint2*>(out)[idx] = make_uint2(lo, hi);
}

// ---------------- fp32 (K x N) -> bf16 transposed (N x K), 4 weights fused ----------------
__global__ void wconv_t4(const float* __restrict__ W0, const float* __restrict__ W1,
                         const float* __restrict__ W2, const float* __restrict__ W3,
                         unsigned short* __restrict__ O0, unsigned short* __restrict__ O1,
                         unsigned short* __restrict__ O2, unsigned short* __restrict__ O3) {
    __shared__ unsigned short tile[32][33];
    int z = blockIdx.z;
    const float* W = (z == 0) ? W0 : (z == 1) ? W1 : (z == 2) ? W2 : W3;
    unsigned short* Wt = (z == 0) ? O0 : (z == 1) ? O1 : (z == 2) ? O2 : O3;
    int n0 = blockIdx.x * 32;
    int k0 = blockIdx.y * 32;
    int t = threadIdx.x;
    int ir = t >> 3, ic = (t & 7) * 4;
    float4 v = *reinterpret_cast<const float4*>(&W[(size_t)(k0 + ir) * DM + n0 + ic]);
    tile[ir][ic + 0] = f2bf(v.x);
    tile[ir][ic + 1] = f2bf(v.y);
    tile[ir][ic + 2] = f2bf(v.z);
    tile[ir][ic + 3] = f2bf(v.w);
    __syncthreads();
    unsigned lo = (unsigned)tile[ic + 0][ir] | ((unsigned)tile[ic + 1][ir] << 16);
    unsigned hi = (unsigned)tile[ic + 2][ir] | ((unsigned)tile[ic + 3][ir] << 16);
    *reinterpret_cast<uint2*>(&Wt[(size_t)(n0 + ir) * DM + k0 + ic]) = make_uint2(lo, hi);
}

// ---------------- bf16 GEMM, m97-style async staging + XOR swizzle ----------------
// MODE 0: fused QKV (Bt N=6144); bf16 out to (which,B,H,S,Ld), LDS-bounced coalesced stores
// MODE 1: fp32 row-major M x 2048 (final output)
template<int MODE>
__global__ __launch_bounds__(256, 2) void gemm_bf16(
    const unsigned short* __restrict__ A,
    const unsigned short* __restrict__ Bt,
    const float* __restrict__ b0, const float* __restrict__ b1,
    const float* __restrict__ b2,
    void* __restrict__ outp)
{
    const int K = DM;
    __shared__ __attribute__((aligned(16))) unsigned short As[128 * 32];
    __shared__ __attribute__((aligned(16))) unsigned short Bs[128 * 32];
    int t = threadIdx.x;
    int m0 = blockIdx.y * 128, n0 = blockIdx.x * 128;
    int lane = t & 63, i16 = lane & 15, quad = lane >> 4;
    int w = t >> 6;
    int wm = (w >> 1) * 64, wn = (w & 1) * 64;

    f32x4 acc[4][4];
    const f32x4 z4 = {0.f, 0.f, 0.f, 0.f};
    for (int mi = 0; mi < 4; ++mi)
        for (int ni = 0; ni < 4; ++ni) acc[mi][ni] = z4;

    for (int kk = 0; kk < K; kk += 32) {
        __syncthreads();
#pragma unroll
        for (int j = 0; j < 2; ++j) {
            int off = j * 4096 + w * 1024 + lane * 16;
            int row = off >> 6;
            int g = ((off >> 4) & 3) ^ ((row >> 1) & 3);
            ld_lds16(&A [(size_t)(m0 + row) * K + kk + g * 8], (char*)As + off);
            ld_lds16(&Bt[(size_t)(n0 + row) * K + kk + g * 8], (char*)Bs + off);
        }
        __syncthreads();

        bf16x8 aF[4], bF[4];
#pragma unroll
        for (int mi = 0; mi < 4; ++mi) {
            int rA = wm + mi * 16 + i16;
            aF[mi] = *reinterpret_cast<const bf16x8*>(
                (const char*)As + rA * 64 + ((quad ^ ((rA >> 1) & 3)) * 16));
        }
#pragma unroll
        for (int ni = 0; ni < 4; ++ni) {
            int rB = wn + ni * 16 + i16;
            bF[ni] = *reinterpret_cast<const bf16x8*>(
                (const char*)Bs + rB * 64 + ((quad ^ ((rB >> 1) & 3)) * 16));
        }
#pragma unroll
        for (int mi = 0; mi < 4; ++mi)
#pragma unroll
            for (int ni = 0; ni < 4; ++ni)
                acc[mi][ni] = MFMA_BF16(aF[mi], bF[ni], acc[mi][ni]);
    }

    if constexpr (MODE == 0) {
        // epilogue via LDS bounce -> coalesced b128 stores
        __shared__ __attribute__((aligned(16))) unsigned short Cs[128 * 128];
        __syncthreads();
        int which = n0 >> 11;
        const float* bp = (which == 0) ? b0 : ((which == 1) ? b1 : b2);
        for (int mi = 0; mi < 4; ++mi) {
            for (int ni = 0; ni < 4; ++ni) {
                int nl = wn + ni * 16 + i16;
                float bv = bp[(n0 & (DM - 1)) + nl];
                for (int r = 0; r < 4; ++r) {
                    int ml = wm + mi * 16 + quad * 4 + r;
                    Cs[ml * 128 + nl] = f2bf(acc[mi][ni][r] + bv);
                }
            }
        }
        __syncthreads();
        int hh = (n0 & (DM - 1)) >> 7;  // head, uniform per block
#pragma unroll
        for (int it = 0; it < 8; ++it) {
            int idx = it * 256 + t;
            int row = idx >> 4, c16 = idx & 15;
            int mm = m0 + row;
            int bb = mm >> 11, ss = mm & (S_LEN - 1);
            size_t oidx = ((((size_t)which * BATCH + bb) * NHEAD + hh) * S_LEN + ss) * LDH + c16 * 8;
            *reinterpret_cast<uint4*>((unsigned short*)outp + oidx) =
                *reinterpret_cast<const uint4*>(Cs + row * 128 + c16 * 8);
        }
    } else {
        for (int mi = 0; mi < 4; ++mi) {
            for (int ni = 0; ni < 4; ++ni) {
                int nn = n0 + wn + ni * 16 + i16;
                float bv = b0[nn];
                for (int r = 0; r < 4; ++r) {
                    int mm = m0 + wm + mi * 16 + quad * 4 + r;
                    ((float*)outp)[(size_t)mm * DM + nn] = acc[mi][ni][r] + bv;
                }
            }
        }
    }
}

// ---------------- RoPE in place; q pre-scaled by (1/sqrt(Ld))*log2(e) ----------------
__global__ void rope_kernel(unsigned short* __restrict__ q, unsigned short* __restrict__ k) {
    int w = threadIdx.x >> 6, lane = threadIdx.x & 63;
    int rowid = blockIdx.x * 4 + w;
    bool isq = (rowid < BATCH * NHEAD * S_LEN);
    unsigned short* base = isq ? q : k;
    int idx = rowid & (BATCH * NHEAD * S_LEN - 1);
    int s = idx & (S_LEN - 1);
    unsigned short* row = base + (size_t)idx * LDH;
    unsigned pair = reinterpret_cast<unsigned*>(row)[lane];
    float x1 = bf2f((unsigned short)(pair & 0xffff));
    float x2 = bf2f((unsigned short)(pair >> 16));
    float freq = (float)exp(-(double)(2 * lane) / 128.0 * 9.210340371976184);
    float angle = (float)s * freq;
    float c = cosf(angle), sn = sinf(angle);
    // fold softmax scale and log2(e) into q so attention uses exp2 directly
    float sc = isq ? (0.08838834764831845f * 1.4426950408889634f) : 1.0f;
    row[lane]      = f2bf((x1 * c - x2 * sn) * sc);
    row[64 + lane] = f2bf((x1 * sn + x2 * c) * sc);
}

// ---------------- V (B,H,S,Ld) -> Vt (B,H,Ld,S) ----------------
__global__ void vtrans(const unsigned short* __restrict__ v, unsigned short* __restrict__ vt) {
    __shared__ unsigned short tile[32][33];
    int bh = blockIdx.z;
    int s0 = blockIdx.x * 32, d0 = blockIdx.y * 32;
    const unsigned short* vin = v + (size_t)bh * S_LEN * LDH;
    unsigned short* vout = vt + (size_t)bh * S_LEN * LDH;
    int t = threadIdx.x;
    int ir = t >> 3, ic = (t & 7) * 4;
    uint2 rv = *reinterpret_cast<const uint2*>(&vin[(size_t)(s0 + ir) * LDH + d0 + ic]);
    tile[ir][ic + 0] = (unsigned short)(rv.x & 0xffff);
    tile[ir][ic + 1] = (unsigned short)(rv.x >> 16);
    tile[ir][ic + 2] = (unsigned short)(rv.y & 0xffff);
    tile[ir][ic + 3] = (unsigned short)(rv.y >> 16);
    __syncthreads();
    unsigned lo = (unsigned)tile[ic + 0][ir] | ((unsigned)tile[ic + 1][ir] << 16);
    unsigned hi = (unsigned)tile[ic + 2][ir] | ((unsigned)tile[ic + 3][ir] << 16);
    *reinterpret_cast<uint2*>(&vout[(size_t)(d0 + ir) * S_LEN + s0 + ic]) = make_uint2(lo, hi);
}

// ---------------- flash attention v3 (anti-causal: keep k >= q) ----------------
// 128 q-rows/block, 4 waves x 32 rows. Swapped QK operands: P lands with
// 4-consecutive keys/lane -> b64 P writes; single l-sum/lane, reduced once.
// Pair-ordered grid: block c and c+256 get q-panels x and 15-x (balanced CUs).
__global__ __launch_bounds__(256, 2) void attn_kernel(
    const unsigned short* __restrict__ q,
    const unsigned short* __restrict__ k,
    const unsigned short* __restrict__ vt,
    unsigned short* __restrict__ att)
{
    __shared__ __attribute__((aligned(16))) unsigned short Ks[64 * 128];  // key-major, swizzled
    __shared__ __attribute__((aligned(16))) unsigned short Vs[128 * 64];  // d-major, swizzled
    __shared__ __attribute__((aligned(16))) unsigned short Ps[4 * 32 * 64];

    int bid = blockIdx.x;
    int second = bid >> 8;
    int p = bid & 255;
    int xb = second ? (15 - (p >> 5)) : (p >> 5);
    int bh = p & 31;
    int b = bh >> 4, h = bh & (NHEAD - 1);
    int q0 = xb * 128;

    int t = threadIdx.x, w = t >> 6, lane = t & 63;
    int i16 = lane & 15, quad = lane >> 4;
    int qbase = q0 + w * 32;

    bf16x8 qf[2][4];
#pragma unroll
    for (int qs = 0; qs < 2; ++qs) {
        const unsigned short* qrow = q + ((size_t)bh * S_LEN + qbase + qs * 16 + i16) * LDH;
#pragma unroll
        for (int c = 0; c < 4; ++c)
            qf[qs][c] = *reinterpret_cast<const bf16x8*>(qrow + c * 32 + quad * 8);
    }

    const f32x4 z4 = {0.f, 0.f, 0.f, 0.f};
    f32x4 o[2][8];
#pragma unroll
    for (int qs = 0; qs < 2; ++qs)
#pragma unroll
        for (int dt = 0; dt < 8; ++dt) o[qs][dt] = z4;
    float l_i[2] = {0.f, 0.f};

    const unsigned short* kbh  = k  + (size_t)bh * S_LEN * LDH;
    const unsigned short* vtbh = vt + (size_t)bh * LDH * S_LEN;
    unsigned short* PsW = Ps + w * (32 * 64);

    for (int kk0 = q0; kk0 < S_LEN; kk0 += 64) {
        __syncthreads();
#pragma unroll
        for (int j = 0; j < 4; ++j) {
            int off = j * 4096 + w * 1024 + lane * 16;
            int key = off >> 8;
            int gk = ((off >> 4) & 15) ^ (key & 15);
            ld_lds16(&kbh[(size_t)(kk0 + key) * LDH + gk * 8], (char*)Ks + off);
            int d = off >> 7;
            int gv = ((off >> 4) & 7) ^ (d & 7);
            ld_lds16(&vtbh[(size_t)d * S_LEN + kk0 + gv * 8], (char*)Vs + off);
        }
        __syncthreads();

        if (kk0 + 64 <= qbase) continue;  // wave fully masked (all keys < all q)

        // QK^T: A=K (m=key), B=Q (n=q)
        f32x4 s[2][4];
#pragma unroll
        for (int qs = 0; qs < 2; ++qs)
#pragma unroll
            for (int kn = 0; kn < 4; ++kn) s[qs][kn] = z4;
#pragma unroll
        for (int c = 0; c < 4; ++c) {
            bf16x8 kf[4];
#pragma unroll
            for (int kn = 0; kn < 4; ++kn) {
                int key = kn * 16 + i16;
                int gs = (c * 4 + quad) ^ (key & 15);
                kf[kn] = *reinterpret_cast<const bf16x8*>((const char*)Ks + key * 256 + gs * 16);
            }
#pragma unroll
            for (int qs = 0; qs < 2; ++qs)
#pragma unroll
                for (int kn = 0; kn < 4; ++kn)
                    s[qs][kn] = MFMA_BF16(kf[kn], qf[qs][c], s[qs][kn]);
        }

        // softmax: per lane q = i16, keys quad*4+r (+16*kn); b64 P writes
        bool diag = (kk0 < qbase + 32);
#pragma unroll
        for (int qs = 0; qs < 2; ++qs) {
            int q_local = qs * 16 + i16;
            int qg = qbase + q_local;
#pragma unroll
            for (int kn = 0; kn < 4; ++kn) {
                int keyb = kk0 + kn * 16 + quad * 4;
                float pv[4];
                if (diag) {
#pragma unroll
                    for (int r = 0; r < 4; ++r)
                        pv[r] = (keyb + r >= qg) ? fexp2(s[qs][kn][r]) : 0.f;
                } else {
#pragma unroll
                    for (int r = 0; r < 4; ++r) pv[r] = fexp2(s[qs][kn][r]);
                }
                l_i[qs] += (pv[0] + pv[1]) + (pv[2] + pv[3]);
                unsigned lo = (unsigned)f2bf(pv[0]) | ((unsigned)f2bf(pv[1]) << 16);
                unsigned hi = (unsigned)f2bf(pv[2]) | ((unsigned)f2bf(pv[3]) << 16);
                int g = (kn * 2 + (quad >> 1)) ^ (q_local & 7);
                char* addr = (char*)PsW + q_local * 128 + g * 16 + (quad & 1) * 8;
                *reinterpret_cast<uint2*>(addr) = make_uint2(lo, hi);
            }
        }

        // PV: A=P (m=q), B=Vt (n=d); per-wave Ps, no barrier needed
#pragma unroll
        for (int hh = 0; hh < 2; ++hh) {
            bf16x8 pf[2];
#pragma unroll
            for (int qs = 0; qs < 2; ++qs) {
                int q_local = qs * 16 + i16;
                int g = (hh * 4 + quad) ^ (q_local & 7);
                pf[qs] = *reinterpret_cast<const bf16x8*>((const char*)PsW + q_local * 128 + g * 16);
            }
#pragma unroll
            for (int dt = 0; dt < 8; ++dt) {
                int d = dt * 16 + i16;
                int gv = (hh * 4 + quad) ^ (d & 7);
                bf16x8 vf = *reinterpret_cast<const bf16x8*>((const char*)Vs + d * 128 + gv * 16);
                o[0][dt] = MFMA_BF16(pf[0], vf, o[0][dt]);
                o[1][dt] = MFMA_BF16(pf[1], vf, o[1][dt]);
            }
        }
    }

    // reduce l across quads (lanes sharing i16), broadcast, normalize, store
#pragma unroll
    for (int qs = 0; qs < 2; ++qs) {
        float lr = l_i[qs];
        lr += __shfl_xor(lr, 16);
        lr += __shfl_xor(lr, 32);
        l_i[qs] = lr;
    }
#pragma unroll
    for (int qs = 0; qs < 2; ++qs) {
#pragma unroll
        for (int r = 0; r < 4; ++r) {
            float lv = __shfl(l_i[qs], quad * 4 + r);
            float inv = 1.0f / lv;
            int qrow = qbase + qs * 16 + quad * 4 + r;
            unsigned short* orow = att + ((size_t)b * S_LEN + qrow) * DM + h * LDH;
#pragma unroll
            for (int dt = 0; dt < 8; ++dt)
                orow[dt * 16 + i16] = f2bf(o[qs][dt][r] * inv);
        }
    }
}

// ---------------- launcher ----------------
extern "C" void kernel_launch(void* const* d_in, const int* in_sizes, int n_in,
                              void* d_out, int out_size, void* d_ws, size_t ws_size,
                              hipStream_t stream) {
    const float* x  = (const float*)d_in[0];
    const float* Wq = (const float*)d_in[2];
    const float* bq = (const float*)d_in[3];
    const float* Wk = (const float*)d_in[4];
    const float* bk = (const float*)d_in[5];
    const float* Wv = (const float*)d_in[6];
    const float* bv = (const float*)d_in[7];
    const float* Wo = (const float*)d_in[8];
    const float* bo = (const float*)d_in[9];

    char* ws = (char*)d_ws;
    unsigned short* xb  = (unsigned short*)(ws);
    unsigned short* Wqt = (unsigned short*)(ws + 16777216);   // QKV weights contiguous
    unsigned short* Wkt = (unsigned short*)(ws + 25165824);
    unsigned short* Wvt = (unsigned short*)(ws + 33554432);
    unsigned short* Wot = (unsigned short*)(ws + 41943040);
    unsigned short* qb  = (unsigned short*)(ws + 50331648);   // q,k,v contiguous
    unsigned short* kb  = (unsigned short*)(ws + 67108864);
    unsigned short* vb  = (unsigned short*)(ws + 83886080);
    unsigned short* vtb = (unsigned short*)(ws + 100663296);
    unsigned short* att = (unsigned short*)(ws + 117440512);

    convert_f32_bf16<<<8192, 256, 0, stream>>>(x, xb, (BATCH * S_LEN * DM) / 4);
    wconv_t4<<<dim3(64, 64, 4), 256, 0, stream>>>(Wq, Wk, Wv, Wo, Wqt, Wkt, Wvt, Wot);

    // fused QKV projection: M=4096, N=6144, K=2048
    gemm_bf16<0><<<dim3(3 * DM / 128, (BATCH * S_LEN) / 128), 256, 0, stream>>>(
        xb, Wqt, bq, bk, bv, qb);

    rope_kernel<<<(2 * BATCH * NHEAD * S_LEN) / 4, 256, 0, stream>>>(qb, kb);
    vtrans<<<dim3(S_LEN / 32, LDH / 32, BATCH * NHEAD), 256, 0, stream>>>(vb, vtb);

    attn_kernel<<<512, 256, 0, stream>>>(qb, kb, vtb, att);

    // output projection: M=4096, N=2048, K=2048, fp32 out
    gemm_bf16<1><<<dim3(DM / 128, (BATCH * S_LEN) / 128), 256, 0, stream>>>(
        att, Wot, bo, bo, bo, (float*)d_out);
}

// Round 4
// 407.493 us; speedup vs baseline: 1.5181x; 1.0118x over previous
//
#include <hip/hip_runtime.h>
#include <math.h>

typedef __bf16 bf16x8 __attribute__((ext_vector_type(8)));
typedef float f32x4 __attribute__((ext_vector_type(4)));

#define MFMA_BF16(a,b,c) __builtin_amdgcn_mfma_f32_16x16x32_bf16((a),(b),(c),0,0,0)

static constexpr int S_LEN = 2048;
static constexpr int DM    = 2048;
static constexpr int NHEAD = 16;
static constexpr int LDH   = 128;
static constexpr int BATCH = 2;
static constexpr size_t QKV_SEG = (size_t)BATCH * NHEAD * S_LEN * LDH;  // elems per q/k/v

__device__ __forceinline__ unsigned short f2bf(float f) {
    unsigned u = __float_as_uint(f);
    u += 0x7fffu + ((u >> 16) & 1u);
    return (unsigned short)(u >> 16);
}
__device__ __forceinline__ float bf2f(unsigned short h) {
    return __uint_as_float(((unsigned)h) << 16);
}
__device__ __forceinline__ float fexp2(float x) { return exp2f(x); }

__device__ __forceinline__ void ld_lds16(const void* g, void* l) {
    __builtin_amdgcn_global_load_lds(
        (const __attribute__((address_space(1))) unsigned int*)g,
        (__attribute__((address_space(3))) unsigned int*)l, 16, 0, 0);
}

// ---------------- fp32 -> bf16 elementwise (x) ----------------
__global__ void convert_f32_bf16(const float* __restrict__ in,
                                 unsigned short* __restrict__ out, int n4) {
    int idx = blockIdx.x * blockDim.x + threadIdx.x;
    if (idx >= n4) return;
    float4 v = reinterpret_cast<const float4*>(in)[idx];
    unsigned lo = (unsigned)f2bf(v.x) | ((unsigned)f2bf(v.y) << 16);
    unsigned hi = (unsigned)f2bf(v.z) | ((unsigned)f2bf(v.w) << 16);
    reinterpret_cast<uint2*>(out)[idx] = make_uint2(lo, hi);
}

// ---------------- rope cos/sin tables: (S, 64) fp32 each ----------------
__global__ void gen_tab(float* __restrict__ ct, float* __restrict__ st) {
    int i = threadIdx.x & 63;
    int s = blockIdx.x * 4 + (threadIdx.x >> 6);
    float freq = (float)exp(-(double)(2 * i) / 128.0 * 9.210340371976184);
    float a = (float)s * freq;
    ct[s * 64 + i] = cosf(a);
    st[s * 64 + i] = sinf(a);
}

// ---------------- fp32 (K x N) -> bf16 transposed (N x K), 4 weights ----------------
__global__ void wconv_t4(const float* __restrict__ W0, const float* __restrict__ W1,
                         const float* __restrict__ W2, const float* __restrict__ W3,
                         unsigned short* __restrict__ O0, unsigned short* __restrict__ O1,
                         unsigned short* __restrict__ O2, unsigned short* __restrict__ O3) {
    __shared__ unsigned short tile[32][33];
    int z = blockIdx.z;
    const float* W = (z == 0) ? W0 : (z == 1) ? W1 : (z == 2) ? W2 : W3;
    unsigned short* Wt = (z == 0) ? O0 : (z == 1) ? O1 : (z == 2) ? O2 : O3;
    int n0 = blockIdx.x * 32;
    int k0 = blockIdx.y * 32;
    int t = threadIdx.x;
    int ir = t >> 3, ic = (t & 7) * 4;
    float4 v = *reinterpret_cast<const float4*>(&W[(size_t)(k0 + ir) * DM + n0 + ic]);
    tile[ir][ic + 0] = f2bf(v.x);
    tile[ir][ic + 1] = f2bf(v.y);
    tile[ir][ic + 2] = f2bf(v.z);
    tile[ir][ic + 3] = f2bf(v.w);
    __syncthreads();
    unsigned lo = (unsigned)tile[ic + 0][ir] | ((unsigned)tile[ic + 1][ir] << 16);
    unsigned hi = (unsigned)tile[ic + 2][ir] | ((unsigned)tile[ic + 3][ir] << 16);
    *reinterpret_cast<uint2*>(&Wt[(size_t)(n0 + ir) * DM + k0 + ic]) = make_uint2(lo, hi);
}

// ---------------- bf16 GEMM + fused epilogues ----------------
// MODE 0: fused QKV (Bt N=6144); q/k get RoPE (+softmax scale on q), v stored
//         transposed (B,H,Ld,S). All via aliased 32KB Cs bounce.
// MODE 1: fp32 row-major out + bias.
template<int MODE>
__global__ __launch_bounds__(256, 2) void gemm_bf16(
    const unsigned short* __restrict__ A,
    const unsigned short* __restrict__ Bt,
    const float* __restrict__ b0, const float* __restrict__ b1,
    const float* __restrict__ b2,
    const float* __restrict__ ctab, const float* __restrict__ stab,
    void* __restrict__ outp)
{
    const int K = DM;
    constexpr int SMEM_SHORTS = (MODE == 0) ? 16384 : 8192;
    __shared__ __attribute__((aligned(16))) unsigned short smem[SMEM_SHORTS];
    unsigned short* As = smem;            // 128x32
    unsigned short* Bs = smem + 4096;     // 128x32
    int t = threadIdx.x;
    int m0 = blockIdx.y * 128, n0 = blockIdx.x * 128;
    int lane = t & 63, i16 = lane & 15, quad = lane >> 4;
    int w = t >> 6;
    int wm = (w >> 1) * 64, wn = (w & 1) * 64;

    f32x4 acc[4][4];
    const f32x4 z4 = {0.f, 0.f, 0.f, 0.f};
    for (int mi = 0; mi < 4; ++mi)
        for (int ni = 0; ni < 4; ++ni) acc[mi][ni] = z4;

    for (int kk = 0; kk < K; kk += 32) {
        __syncthreads();
#pragma unroll
        for (int j = 0; j < 2; ++j) {
            int off = j * 4096 + w * 1024 + lane * 16;
            int row = off >> 6;
            int g = ((off >> 4) & 3) ^ ((row >> 1) & 3);
            ld_lds16(&A [(size_t)(m0 + row) * K + kk + g * 8], (char*)As + off);
            ld_lds16(&Bt[(size_t)(n0 + row) * K + kk + g * 8], (char*)Bs + off);
        }
        __syncthreads();

        bf16x8 aF[4], bF[4];
#pragma unroll
        for (int mi = 0; mi < 4; ++mi) {
            int rA = wm + mi * 16 + i16;
            aF[mi] = *reinterpret_cast<const bf16x8*>(
                (const char*)As + rA * 64 + ((quad ^ ((rA >> 1) & 3)) * 16));
        }
#pragma unroll
        for (int ni = 0; ni < 4; ++ni) {
            int rB = wn + ni * 16 + i16;
            bF[ni] = *reinterpret_cast<const bf16x8*>(
                (const char*)Bs + rB * 64 + ((quad ^ ((rB >> 1) & 3)) * 16));
        }
#pragma unroll
        for (int mi = 0; mi < 4; ++mi)
#pragma unroll
            for (int ni = 0; ni < 4; ++ni)
                acc[mi][ni] = MFMA_BF16(aF[mi], bF[ni], acc[mi][ni]);
    }

    if constexpr (MODE == 0) {
        unsigned short* Cs = smem;              // alias staging (32KB)
        __syncthreads();                        // staging reads done
        int which = n0 >> 11;                   // 0=q 1=k 2=v (uniform per block)
        int hh = (n0 & (DM - 1)) >> 7;          // head
        const float* bp = (which == 0) ? b0 : ((which == 1) ? b1 : b2);
        if (which == 2) {
            // store transposed (d, s) with XOR-swizzled s-groups
            for (int mi = 0; mi < 4; ++mi)
                for (int ni = 0; ni < 4; ++ni) {
                    int d = wn + ni * 16 + i16;
                    float bv = bp[(n0 & (DM - 1)) + d];
                    for (int r = 0; r < 4; ++r) {
                        int sl = wm + mi * 16 + quad * 4 + r;
                        Cs[d * 128 + (((sl >> 3) ^ (d & 15)) * 8) + (sl & 7)] =
                            f2bf(acc[mi][ni][r] + bv);
                    }
                }
            __syncthreads();
            int s0 = m0 & (S_LEN - 1), bb = m0 >> 11;
            unsigned short* vout = (unsigned short*)outp + 2 * QKV_SEG;
#pragma unroll
            for (int it = 0; it < 8; ++it) {
                int idx = it * 256 + t;
                int d = idx >> 4, sg = idx & 15;
                uint4 v = *reinterpret_cast<const uint4*>(&Cs[d * 128 + ((sg ^ (d & 15)) * 8)]);
                size_t oidx = (((size_t)(bb * NHEAD + hh)) * LDH + d) * S_LEN + s0 + sg * 8;
                *reinterpret_cast<uint4*>(vout + oidx) = v;
            }
        } else {
            // q/k: bounce raw acc+bias, then RoPE on store
            for (int mi = 0; mi < 4; ++mi)
                for (int ni = 0; ni < 4; ++ni) {
                    int nl = wn + ni * 16 + i16;
                    float bv = bp[(n0 & (DM - 1)) + nl];
                    for (int r = 0; r < 4; ++r) {
                        int ml = wm + mi * 16 + quad * 4 + r;
                        Cs[ml * 128 + nl] = f2bf(acc[mi][ni][r] + bv);
                    }
                }
            __syncthreads();
            // fold softmax scale (1/sqrt(128)) * log2(e) into q
            float qscale = (which == 0) ? (0.08838834764831845f * 1.4426950408889634f) : 1.0f;
            unsigned short* qout = (unsigned short*)outp + (size_t)which * QKV_SEG;
#pragma unroll
            for (int it = 0; it < 8; ++it) {
                int idx = it * 256 + t;
                int row = idx >> 4, c16 = idx & 15;
                int mm = m0 + row;
                int ss = mm & (S_LEN - 1), bb = mm >> 11;
                int i8 = (c16 & 7) * 8;
                const unsigned short* crow = Cs + row * 128 + i8 * 2;
                uint4 w0 = *reinterpret_cast<const uint4*>(crow);
                uint4 w1 = *reinterpret_cast<const uint4*>(crow + 8);
                unsigned pw[8] = {w0.x, w0.y, w0.z, w0.w, w1.x, w1.y, w1.z, w1.w};
                float4 cA = *reinterpret_cast<const float4*>(&ctab[ss * 64 + i8]);
                float4 cB = *reinterpret_cast<const float4*>(&ctab[ss * 64 + i8 + 4]);
                float4 sA = *reinterpret_cast<const float4*>(&stab[ss * 64 + i8]);
                float4 sB = *reinterpret_cast<const float4*>(&stab[ss * 64 + i8 + 4]);
                float cv[8] = {cA.x, cA.y, cA.z, cA.w, cB.x, cB.y, cB.z, cB.w};
                float sv[8] = {sA.x, sA.y, sA.z, sA.w, sB.x, sB.y, sB.z, sB.w};
                bool hi = (c16 >= 8);
                unsigned short ov[8];
#pragma unroll
                for (int j = 0; j < 8; ++j) {
                    float xe = bf2f((unsigned short)(pw[j] & 0xffff));
                    float xo = bf2f((unsigned short)(pw[j] >> 16));
                    float o = hi ? (xe * sv[j] + xo * cv[j]) : (xe * cv[j] - xo * sv[j]);
                    ov[j] = f2bf(o * qscale);
                }
                size_t oidx = (((size_t)(bb * NHEAD + hh)) * S_LEN + ss) * LDH + c16 * 8;
                *reinterpret_cast<uint4*>(qout + oidx) =
                    *reinterpret_cast<const uint4*>(ov);
            }
        }
    } else {
        for (int mi = 0; mi < 4; ++mi) {
            for (int ni = 0; ni < 4; ++ni) {
                int nn = n0 + wn + ni * 16 + i16;
                float bv = b0[nn];
                for (int r = 0; r < 4; ++r) {
                    int mm = m0 + wm + mi * 16 + quad * 4 + r;
                    ((float*)outp)[(size_t)mm * DM + nn] = acc[mi][ni][r] + bv;
                }
            }
        }
    }
}

// ---------------- flash attention v4: double-buffered staging ----------------
// anti-causal (keep k >= q); no-max softmax (exp2, scale folded into q);
// 128 q/block, 4 waves x 32 q; 64-key chunks; 1 barrier per chunk with
// async prefetch of chunk i+1 overlapping compute of chunk i.
__global__ __launch_bounds__(256, 2) void attn_kernel(
    const unsigned short* __restrict__ q,
    const unsigned short* __restrict__ k,
    const unsigned short* __restrict__ vt,
    unsigned short* __restrict__ att)
{
    __shared__ __attribute__((aligned(16))) unsigned short Ks[2][64 * 128];
    __shared__ __attribute__((aligned(16))) unsigned short Vs[2][128 * 64];
    __shared__ __attribute__((aligned(16))) unsigned short Ps[4][32 * 64];

    int bid = blockIdx.x;
    int second = bid >> 8;
    int p = bid & 255;
    int xb = second ? (15 - (p >> 5)) : (p >> 5);
    int bh = p & 31;
    int b = bh >> 4, h = bh & (NHEAD - 1);
    int q0 = xb * 128;

    int t = threadIdx.x, w = t >> 6, lane = t & 63;
    int i16 = lane & 15, quad = lane >> 4;
    int qbase = q0 + w * 32;

    bf16x8 qf[2][4];
#pragma unroll
    for (int qs = 0; qs < 2; ++qs) {
        const unsigned short* qrow = q + ((size_t)bh * S_LEN + qbase + qs * 16 + i16) * LDH;
#pragma unroll
        for (int c = 0; c < 4; ++c)
            qf[qs][c] = *reinterpret_cast<const bf16x8*>(qrow + c * 32 + quad * 8);
    }

    const f32x4 z4 = {0.f, 0.f, 0.f, 0.f};
    f32x4 o[2][8];
#pragma unroll
    for (int qs = 0; qs < 2; ++qs)
#pragma unroll
        for (int dt = 0; dt < 8; ++dt) o[qs][dt] = z4;
    float l_i[2] = {0.f, 0.f};

    const unsigned short* kbh  = k  + (size_t)bh * S_LEN * LDH;
    const unsigned short* vtbh = vt + (size_t)bh * LDH * S_LEN;
    unsigned short* PsW = Ps[w];

    auto stage = [&](int buf, int kk0) {
#pragma unroll
        for (int j = 0; j < 4; ++j) {
            int off = j * 4096 + w * 1024 + lane * 16;
            int key = off >> 8;
            int gk = ((off >> 4) & 15) ^ (key & 15);
            ld_lds16(&kbh[(size_t)(kk0 + key) * LDH + gk * 8], (char*)Ks[buf] + off);
            int d = off >> 7;
            int gv = ((off >> 4) & 7) ^ (d & 7);
            ld_lds16(&vtbh[(size_t)d * S_LEN + kk0 + gv * 8], (char*)Vs[buf] + off);
        }
    };

    stage(0, q0);
    int nch = (S_LEN - q0) >> 6;
    for (int ci = 0; ci < nch; ++ci) {
        __syncthreads();   // drains this wave's vmcnt -> buf[ci&1] ready; guards buf reuse
        if (ci + 1 < nch) stage((ci + 1) & 1, q0 + (ci + 1) * 64);
        int kk0 = q0 + ci * 64;
        if (kk0 + 64 <= qbase) continue;   // wave fully masked
        const unsigned short* Kb = Ks[ci & 1];
        const unsigned short* Vb = Vs[ci & 1];

        // QK^T: A=K (m=key), B=Q (n=q)
        f32x4 s[2][4];
#pragma unroll
        for (int qs = 0; qs < 2; ++qs)
#pragma unroll
            for (int kn = 0; kn < 4; ++kn) s[qs][kn] = z4;
#pragma unroll
        for (int c = 0; c < 4; ++c) {
            bf16x8 kf[4];
#pragma unroll
            for (int kn = 0; kn < 4; ++kn) {
                int key = kn * 16 + i16;
                int gs = (c * 4 + quad) ^ (key & 15);
                kf[kn] = *reinterpret_cast<const bf16x8*>((const char*)Kb + key * 256 + gs * 16);
            }
#pragma unroll
            for (int qs = 0; qs < 2; ++qs)
#pragma unroll
                for (int kn = 0; kn < 4; ++kn)
                    s[qs][kn] = MFMA_BF16(kf[kn], qf[qs][c], s[qs][kn]);
        }

        bool diag = (kk0 < qbase + 32);
#pragma unroll
        for (int qs = 0; qs < 2; ++qs) {
            int q_local = qs * 16 + i16;
            int qg = qbase + q_local;
#pragma unroll
            for (int kn = 0; kn < 4; ++kn) {
                int keyb = kk0 + kn * 16 + quad * 4;
                float pv[4];
                if (diag) {
#pragma unroll
                    for (int r = 0; r < 4; ++r)
                        pv[r] = (keyb + r >= qg) ? fexp2(s[qs][kn][r]) : 0.f;
                } else {
#pragma unroll
                    for (int r = 0; r < 4; ++r) pv[r] = fexp2(s[qs][kn][r]);
                }
                l_i[qs] += (pv[0] + pv[1]) + (pv[2] + pv[3]);
                unsigned lo = (unsigned)f2bf(pv[0]) | ((unsigned)f2bf(pv[1]) << 16);
                unsigned hi = (unsigned)f2bf(pv[2]) | ((unsigned)f2bf(pv[3]) << 16);
                int g = (kn * 2 + (quad >> 1)) ^ (q_local & 7);
                char* addr = (char*)PsW + q_local * 128 + g * 16 + (quad & 1) * 8;
                *reinterpret_cast<uint2*>(addr) = make_uint2(lo, hi);
            }
        }

        // PV: A=P (m=q), B=Vt (n=d); Ps per-wave -> no barrier
#pragma unroll
        for (int hh = 0; hh < 2; ++hh) {
            bf16x8 pf[2];
#pragma unroll
            for (int qs = 0; qs < 2; ++qs) {
                int q_local = qs * 16 + i16;
                int g = (hh * 4 + quad) ^ (q_local & 7);
                pf[qs] = *reinterpret_cast<const bf16x8*>((const char*)PsW + q_local * 128 + g * 16);
            }
#pragma unroll
            for (int dt = 0; dt < 8; ++dt) {
                int d = dt * 16 + i16;
                int gv = (hh * 4 + quad) ^ (d & 7);
                bf16x8 vf = *reinterpret_cast<const bf16x8*>((const char*)Vb + d * 128 + gv * 16);
                o[0][dt] = MFMA_BF16(pf[0], vf, o[0][dt]);
                o[1][dt] = MFMA_BF16(pf[1], vf, o[1][dt]);
            }
        }
    }

#pragma unroll
    for (int qs = 0; qs < 2; ++qs) {
        float lr = l_i[qs];
        lr += __shfl_xor(lr, 16);
        lr += __shfl_xor(lr, 32);
        l_i[qs] = lr;
    }
#pragma unroll
    for (int qs = 0; qs < 2; ++qs) {
#pragma unroll
        for (int r = 0; r < 4; ++r) {
            float lv = __shfl(l_i[qs], quad * 4 + r);
            float inv = 1.0f / lv;
            int qrow = qbase + qs * 16 + quad * 4 + r;
            unsigned short* orow = att + ((size_t)b * S_LEN + qrow) * DM + h * LDH;
#pragma unroll
            for (int dt = 0; dt < 8; ++dt)
                orow[dt * 16 + i16] = f2bf(o[qs][dt][r] * inv);
        }
    }
}

// ---------------- launcher ----------------
extern "C" void kernel_launch(void* const* d_in, const int* in_sizes, int n_in,
                              void* d_out, int out_size, void* d_ws, size_t ws_size,
                              hipStream_t stream) {
    const float* x  = (const float*)d_in[0];
    const float* Wq = (const float*)d_in[2];
    const float* bq = (const float*)d_in[3];
    const float* Wk = (const float*)d_in[4];
    const float* bk = (const float*)d_in[5];
    const float* Wv = (const float*)d_in[6];
    const float* bv = (const float*)d_in[7];
    const float* Wo = (const float*)d_in[8];
    const float* bo = (const float*)d_in[9];

    char* ws = (char*)d_ws;
    unsigned short* xb  = (unsigned short*)(ws);                  // 16 MB
    unsigned short* Wqt = (unsigned short*)(ws + 16777216);       // QKV weights contiguous
    unsigned short* Wkt = (unsigned short*)(ws + 25165824);
    unsigned short* Wvt = (unsigned short*)(ws + 33554432);
    unsigned short* Wot = (unsigned short*)(ws + 41943040);
    unsigned short* qkv = (unsigned short*)(ws + 50331648);       // q | k | v^T, 16 MB each
    unsigned short* att = (unsigned short*)(ws + 100663296);
    float* ctab = (float*)(ws + 117440512);                       // 512 KB
    float* stab = (float*)(ws + 117964800);                       // 512 KB

    convert_f32_bf16<<<8192, 256, 0, stream>>>(x, xb, (BATCH * S_LEN * DM) / 4);
    gen_tab<<<512, 256, 0, stream>>>(ctab, stab);
    wconv_t4<<<dim3(64, 64, 4), 256, 0, stream>>>(Wq, Wk, Wv, Wo, Wqt, Wkt, Wvt, Wot);

    // fused QKV projection + RoPE + V-transpose: M=4096, N=6144, K=2048
    gemm_bf16<0><<<dim3(3 * DM / 128, (BATCH * S_LEN) / 128), 256, 0, stream>>>(
        xb, Wqt, bq, bk, bv, ctab, stab, qkv);

    attn_kernel<<<512, 256, 0, stream>>>(qkv, qkv + QKV_SEG, qkv + 2 * QKV_SEG, att);

    // output projection: M=4096, N=2048, K=2048, fp32 out
    gemm_bf16<1><<<dim3(DM / 128, (BATCH * S_LEN) / 128), 256, 0, stream>>>(
        att, Wot, bo, bo, bo, ctab, stab, (float*)d_out);
}